// Round 5
// baseline (197.069 us; speedup 1.0000x reference)
//
#include <hip/hip_runtime.h>
#include <math.h>

namespace {
constexpr int BATCH = 4;
constexpr int DDIM  = 128;
constexpr int HDIM  = 192;
constexpr int WDIM  = 192;
constexpr long long NTOT = (long long)BATCH * DDIM * HDIM * WDIM; // 18,874,368
constexpr int GW    = WDIM / 4;            // 48 float4 groups per W-row
constexpr int NDSC  = 4 * 1 * 8 * 12 * 12; // 4608
constexpr int TH    = 8;                   // compute rows per block
constexpr int SROWS = TH + 2;              // staged rows (H halo)
constexpr int SGRP  = SROWS * GW;          // 480 float4 groups / slab
constexpr int SFL   = SGRP * 4;            // 1920 floats / slab (7680 B, contiguous)
constexpr int BLOCK = TH * GW;             // 384 threads = 6 waves
constexpr int NWAVE = BLOCK / 64;          // 6
constexpr int NCHUNK = (SGRP + 63) / 64;   // 8 wave-chunks (last overlaps back)
constexpr int DC    = 16;                  // depth steps per block
constexpr int GRID  = BATCH * (HDIM / TH) * (DDIM / DC); // 768 = 3 blocks/CU
}

__device__ __forceinline__ float4 ld4(const float* __restrict__ p, long long g) {
    return *(const float4*)(p + 4LL * g);
}

// Async-DMA one contiguous slab (SROWS full-W rows at one depth) into LDS.
// LDS dest is wave-uniform base + lane*16 (HW constraint), which matches the
// slab's contiguous global layout exactly. Last chunk is aligned backward
// (overlap-writes identical data) so no lane goes out of bounds.
__device__ __forceinline__ void stage(const float* __restrict__ vol, long long fbase,
                                      float* lds, int wave, int lane) {
    for (int c = wave; c < NCHUNK; c += NWAVE) {
        const int gbase = (c == NCHUNK - 1) ? (SGRP - 64) : (c * 64);
        const float* g = vol + fbase + 4LL * (gbase + lane);
        __builtin_amdgcn_global_load_lds(
            (const __attribute__((address_space(1))) void*)g,
            (__attribute__((address_space(3))) void*)(lds + 4 * gbase),
            16, 0, 0);
    }
}

// Block tile: TH rows x full W x DC depths. 3-buffer LDS ring along D:
// while computing plane d (H-nbrs from cur slab, D-nbrs from register
// pipeline, W-nbrs via shuffle + 2-lane LDS patch), DMA plane d+2 into the
// free slab. np.gradient edges branchless: clamp + scale (1 edge / 0.5 int.).
__global__ __launch_bounds__(BLOCK) void vol_kernel(const float* __restrict__ p,
                                                    const float* __restrict__ y,
                                                    float* __restrict__ part) {
    __shared__ __align__(16) float smem[3][2][SFL];   // 46,080 B

    int bid = blockIdx.x;
    const int dIdx = bid % (DDIM / DC); bid /= (DDIM / DC);
    const int hIdx = bid % (HDIM / TH); bid /= (HDIM / TH);
    const int b    = bid;
    const int d0   = dIdx * DC;
    const int h0   = hIdx * TH;

    const int tid  = threadIdx.x;
    const int lane = tid & 63;
    const int wave = tid >> 6;
    const int r    = tid / GW;
    const int gw   = tid % GW;
    const int h    = h0 + r;

    // slab row window: clamp at volume H edges
    const int g0     = (h0 == 0) ? 0 : ((h0 == HDIM - TH) ? (HDIM - SROWS) : (h0 - 1));
    const int rowOff = h0 - g0;                  // 0 / 1 / 2
    const int sf     = ((r + rowOff) * GW + gw) * 4;  // own float offset in slab

    const int   hmF = ((h == 0)        ? 0 : -GW) * 4;
    const int   hpF = ((h == HDIM - 1) ? 0 :  GW) * 4;
    const float sh  = (h == 0 || h == HDIM - 1) ? 1.f : 0.5f;
    const float swx = (gw == 0)      ? 1.f : 0.5f;
    const float sww = (gw == GW - 1) ? 1.f : 0.5f;
    const bool needL = (lane == 0)  && (gw > 0);
    const bool needR = (lane == 63) && (gw < GW - 1);

    const long long planeStride = (long long)HDIM * WDIM;
    const long long volBase = (long long)b * DDIM * planeStride + (long long)g0 * WDIM;

    float* curY = &smem[0][0][0]; float* curP = &smem[0][1][0];
    float* nxtY = &smem[1][0][0]; float* nxtP = &smem[1][1][0];
    float* freY = &smem[2][0][0]; float* freP = &smem[2][1][0];

    // prologue: DMA S[d0], S[d0+1]; own-column ym from global (clamped)
    stage(y, volBase + (long long)d0 * planeStride, curY, wave, lane);
    stage(p, volBase + (long long)d0 * planeStride, curP, wave, lane);
    stage(y, volBase + (long long)(d0 + 1) * planeStride, nxtY, wave, lane);
    stage(p, volBase + (long long)(d0 + 1) * planeStride, nxtP, wave, lane);

    const int dm = (d0 > 0) ? (d0 - 1) : 0;
    const long long gown = (((long long)b * DDIM + dm) * HDIM + h) * GW + gw;
    float4 ym = ld4(y, gown), pm = ld4(p, gown);

    float l1 = 0.f, gd = 0.f;
    float4 yc, pc;

    for (int i = 0; i < DC; ++i) {
        const int d = d0 + i;
        __syncthreads();   // drains this wave's DMA (incl. S[d+1]) + frees 'fre'
        if (i == 0) {
            yc = *(const float4*)(curY + sf);
            pc = *(const float4*)(curP + sf);
        }
        if (i + 2 <= DC) { // kick S[d+2] into the free slab; flies during compute
            const int dd = (d0 + i + 2 < DDIM) ? (d0 + i + 2) : (DDIM - 1);
            stage(y, volBase + (long long)dd * planeStride, freY, wave, lane);
            stage(p, volBase + (long long)dd * planeStride, freP, wave, lane);
        }

        const float4 yn  = *(const float4*)(nxtY + sf);
        const float4 pn  = *(const float4*)(nxtP + sf);
        const float4 yhm = *(const float4*)(curY + sf + hmF);
        const float4 yhp = *(const float4*)(curY + sf + hpF);
        const float4 phm = *(const float4*)(curP + sf + hmF);
        const float4 php = *(const float4*)(curP + sf + hpF);

        // W neighbors: shuffle from register yc/pc + wave-boundary LDS patch
        float Ly = __shfl_up(yc.w, 1, 64);
        float Lp = __shfl_up(pc.w, 1, 64);
        float Ry = __shfl_down(yc.x, 1, 64);
        float Rp = __shfl_down(pc.x, 1, 64);
        if (needL) { Ly = curY[sf - 1]; Lp = curP[sf - 1]; }
        if (needR) { Ry = curY[sf + 4]; Rp = curP[sf + 4]; }
        Ly = gw ? Ly : yc.x;             Lp = gw ? Lp : pc.x;
        Ry = (gw == GW - 1) ? yc.w : Ry; Rp = (gw == GW - 1) ? pc.w : Rp;

        const float sd = (d == 0 || d == DDIM - 1) ? 1.f : 0.5f;

        // ---- L1 ----
        l1 += fabsf(yc.x - pc.x) + fabsf(yc.y - pc.y)
            + fabsf(yc.z - pc.z) + fabsf(yc.w - pc.w);

        float t0, gy, gp;
        // ---- W axis ----
        gy = (yc.y - Ly) * swx;    gp = (pc.y - Lp) * swx;
        t0 = fabsf(gy) - fabsf(gp); gd += t0 * t0;
        gy = (yc.z - yc.x) * 0.5f; gp = (pc.z - pc.x) * 0.5f;
        t0 = fabsf(gy) - fabsf(gp); gd += t0 * t0;
        gy = (yc.w - yc.y) * 0.5f; gp = (pc.w - pc.y) * 0.5f;
        t0 = fabsf(gy) - fabsf(gp); gd += t0 * t0;
        gy = (Ry - yc.z) * sww;    gp = (Rp - pc.z) * sww;
        t0 = fabsf(gy) - fabsf(gp); gd += t0 * t0;

        // ---- H axis (LDS) ----
        t0 = fabsf((yhp.x - yhm.x) * sh) - fabsf((php.x - phm.x) * sh); gd += t0 * t0;
        t0 = fabsf((yhp.y - yhm.y) * sh) - fabsf((php.y - phm.y) * sh); gd += t0 * t0;
        t0 = fabsf((yhp.z - yhm.z) * sh) - fabsf((php.z - phm.z) * sh); gd += t0 * t0;
        t0 = fabsf((yhp.w - yhm.w) * sh) - fabsf((php.w - phm.w) * sh); gd += t0 * t0;

        // ---- D axis (register pipeline) ----
        t0 = fabsf((yn.x - ym.x) * sd) - fabsf((pn.x - pm.x) * sd); gd += t0 * t0;
        t0 = fabsf((yn.y - ym.y) * sd) - fabsf((pn.y - pm.y) * sd); gd += t0 * t0;
        t0 = fabsf((yn.z - ym.z) * sd) - fabsf((pn.z - pm.z) * sd); gd += t0 * t0;
        t0 = fabsf((yn.w - ym.w) * sd) - fabsf((pn.w - pm.w) * sd); gd += t0 * t0;

        // rotate: registers and LDS ring
        ym = yc; yc = yn; pm = pc; pc = pn;
        float* tY = curY; curY = nxtY; nxtY = freY; freY = tY;
        float* tP = curP; curP = nxtP; nxtP = freP; freP = tP;
    }

    // ---- block reduction, one partial pair per block ----
    __shared__ float red1[NWAVE], red2[NWAVE];
    #pragma unroll
    for (int off = 32; off > 0; off >>= 1) {
        l1 += __shfl_down(l1, off, 64);
        gd += __shfl_down(gd, off, 64);
    }
    if (lane == 0) { red1[wave] = l1; red2[wave] = gd; }
    __syncthreads();
    if (tid == 0) {
        float s1 = 0.f, s2 = 0.f;
        #pragma unroll
        for (int w = 0; w < NWAVE; ++w) { s1 += red1[w]; s2 += red2[w]; }
        part[2 * blockIdx.x]     = s1;
        part[2 * blockIdx.x + 1] = s2;
    }
}

// Reduce per-block partials + BCE over the small discriminator tensor.
__global__ __launch_bounds__(256) void finalize_kernel(const float* __restrict__ dsc,
                                                       const float* __restrict__ part,
                                                       float* __restrict__ out) {
    float l1 = 0.f, gd = 0.f, s = 0.f;
    for (int i = threadIdx.x; i < GRID; i += 256) {
        l1 += part[2 * i];
        gd += part[2 * i + 1];
    }
    for (int i = threadIdx.x; i < NDSC; i += 256) {
        const float x = dsc[i];
        // target is zeros: max(x,0) - x*0 + log1p(exp(-|x|))
        s += fmaxf(x, 0.f) + log1pf(expf(-fabsf(x)));
    }
    __shared__ float a[4], c[4], e[4];
    #pragma unroll
    for (int off = 32; off > 0; off >>= 1) {
        l1 += __shfl_down(l1, off, 64);
        gd += __shfl_down(gd, off, 64);
        s  += __shfl_down(s,  off, 64);
    }
    if ((threadIdx.x & 63) == 0) {
        const int w = threadIdx.x >> 6;
        a[w] = l1; c[w] = gd; e[w] = s;
    }
    __syncthreads();
    if (threadIdx.x == 0) {
        const float bce = (e[0] + e[1] + e[2] + e[3]) / (float)NDSC;
        const float l1m = (a[0] + a[1] + a[2] + a[3]) / (float)NTOT;
        const float gdm = (c[0] + c[1] + c[2] + c[3]) / (float)NTOT;
        out[0] = bce + 100.f * (l1m + gdm);
    }
}

extern "C" void kernel_launch(void* const* d_in, const int* in_sizes, int n_in,
                              void* d_out, int out_size, void* d_ws, size_t ws_size,
                              hipStream_t stream) {
    const float* dsc_fake = (const float*)d_in[0];
    const float* predicts = (const float*)d_in[1];
    const float* y_data   = (const float*)d_in[2];
    // d_in[3] (zeros) unused: target==0 makes the -x*target term vanish.
    float* part = (float*)d_ws;   // GRID*2 floats, fully overwritten each call
    float* out  = (float*)d_out;

    vol_kernel<<<GRID, BLOCK, 0, stream>>>(predicts, y_data, part);
    finalize_kernel<<<1, 256, 0, stream>>>(dsc_fake, part, out);
}

// Round 6
// 194.175 us; speedup vs baseline: 1.0149x; 1.0149x over previous
//
#include <hip/hip_runtime.h>
#include <math.h>

namespace {
constexpr int BATCH = 4;
constexpr int DDIM  = 128;
constexpr int HDIM  = 192;
constexpr int WDIM  = 192;
constexpr long long NTOT = (long long)BATCH * DDIM * HDIM * WDIM; // 18,874,368
constexpr int GW    = WDIM / 4;            // 48 float4 groups per W-row
constexpr int NDSC  = 4 * 1 * 8 * 12 * 12; // 4608
constexpr int TH    = 8;                   // computed rows per block
constexpr int SROWS = TH + 2;              // staged rows (H halo)
constexpr int SGRP  = SROWS * GW;          // 480 float4 groups / slab
constexpr int SFL   = SGRP * 4;            // 1920 floats / slab (7680 B)
constexpr int BLOCK = 512;                 // 8 waves so NCHUNK == NWAVE (uniform DMA count)
constexpr int NWAVE = BLOCK / 64;          // 8
constexpr int NCHUNK = (SGRP + 63) / 64;   // 8 (last chunk overlap-aligned back)
constexpr int NCOMP = TH * GW;             // 384 compute threads (waves 0-5)
constexpr int DC    = 16;                  // depth steps per block
constexpr int GRID  = BATCH * (HDIM / TH) * (DDIM / DC); // 768 = 3 blocks/CU
}

__device__ __forceinline__ float4 ld4(const float* __restrict__ p, long long g) {
    return *(const float4*)(p + 4LL * g);
}

// Each wave DMAs exactly one 64-group chunk per volume per plane (2 insts
// total) — uniform vmcnt accounting for every wave. LDS dest = wave-uniform
// base + lane*16 (HW constraint), matching the slab's contiguous layout.
__device__ __forceinline__ void stage2(const float* __restrict__ y,
                                       const float* __restrict__ p,
                                       long long fbase,
                                       float* ldsY, float* ldsP,
                                       int wave, int lane) {
    const int gbase = (wave == NCHUNK - 1) ? (SGRP - 64) : (wave * 64);
    __builtin_amdgcn_global_load_lds(
        (const __attribute__((address_space(1))) void*)(y + fbase + 4LL * (gbase + lane)),
        (__attribute__((address_space(3))) void*)(ldsY + 4 * gbase), 16, 0, 0);
    __builtin_amdgcn_global_load_lds(
        (const __attribute__((address_space(1))) void*)(p + fbase + 4LL * (gbase + lane)),
        (__attribute__((address_space(3))) void*)(ldsP + 4 * gbase), 16, 0, 0);
}

// Fine-vmcnt plane pipeline (no __syncthreads in the hot loop):
//   iter i visits plane v=d0+i (i=0..DC):
//     s_waitcnt vmcnt(2) lgkmcnt(0)   -> own plane-v chunks landed; plane v+1 in flight
//     s_barrier (raw asm, no drain)   -> everyone's plane-v landed; slab (i-1)%3 free
//     issue DMA plane v+2 -> slab (i+2)%3
//     read plane v from slab i%3; fold L1 + W/H grads for depth v (i<DC);
//     fold deferred D grad for depth v-1 from register pipeline (i>=1).
// vmcnt(2) is exact: each wave issues 2 DMAs/plane; the plane-v batch is the
// oldest outstanding (in-order vmcnt retirement), so waiting to depth 2 drains
// exactly plane v while keeping plane v+1 in flight (~2 compute phases of
// latency hiding). lgkmcnt(0) closes the pending-ds_read vs DMA-overwrite race.
__global__ __launch_bounds__(BLOCK, 6) void vol_kernel(const float* __restrict__ p,
                                                       const float* __restrict__ y,
                                                       float* __restrict__ part) {
    __shared__ __align__(16) float smem[3][2][SFL];   // 46,080 B -> 3 blocks/CU

    int bid = blockIdx.x;
    const int dIdx = bid % (DDIM / DC); bid /= (DDIM / DC);
    const int hIdx = bid % (HDIM / TH); bid /= (HDIM / TH);
    const int b    = bid;
    const int d0   = dIdx * DC;
    const int h0   = hIdx * TH;

    const int tid  = threadIdx.x;
    const int lane = tid & 63;
    const int wave = tid >> 6;
    const bool comp = (tid < NCOMP);   // wave-uniform: waves 0-5 compute

    const int g0 = (h0 == 0) ? 0 : ((h0 == HDIM - TH) ? (HDIM - SROWS) : (h0 - 1));
    const long long planeStride = (long long)HDIM * WDIM;
    const long long volBase = (long long)b * DDIM * planeStride + (long long)g0 * WDIM;

    // prologue: DMA planes d0, d0+1 (d0+1 <= 113 < 128 always)
    stage2(y, p, volBase + (long long)d0 * planeStride,
           &smem[0][0][0], &smem[0][1][0], wave, lane);
    stage2(y, p, volBase + (long long)(d0 + 1) * planeStride,
           &smem[1][0][0], &smem[1][1][0], wave, lane);

    // per-thread compute constants (garbage-but-unused for tid >= NCOMP)
    const int r  = tid / GW;
    const int gw = tid % GW;
    const int h  = h0 + r;
    const int rowOff = h0 - g0;                      // 0 / 1 / 2
    const int sf  = ((r + rowOff) * GW + gw) * 4;    // own float offset in slab
    const int hmF = ((h == 0)        ? 0 : -GW) * 4;
    const int hpF = ((h == HDIM - 1) ? 0 :  GW) * 4;
    const float sh  = (h == 0 || h == HDIM - 1) ? 1.f : 0.5f;
    const float swx = (gw == 0)      ? 1.f : 0.5f;
    const float sww = (gw == GW - 1) ? 1.f : 0.5f;
    const bool needL = (lane == 0)  && (gw > 0);
    const bool needR = (lane == 63) && (gw < GW - 1);

    // register D-pipeline: cm1 = c(d0-1) (clamped), becomes cm2 at iter 1
    float4 cm2y, cm1y, cm2p, cm1p;
    if (comp) {
        const int dm = (d0 > 0) ? (d0 - 1) : 0;
        const long long gown = (((long long)b * DDIM + dm) * HDIM + h) * GW + gw;
        cm1y = ld4(y, gown); cm1p = ld4(p, gown);
    }

    float l1 = 0.f, gd = 0.f;

    for (int i = 0; i <= DC; ++i) {
        if (i < DC) asm volatile("s_waitcnt vmcnt(2) lgkmcnt(0)" ::: "memory");
        else        asm volatile("s_waitcnt vmcnt(0) lgkmcnt(0)" ::: "memory");
        asm volatile("s_barrier" ::: "memory");

        if (i + 2 <= DC) {
            int dd = d0 + i + 2; if (dd > DDIM - 1) dd = DDIM - 1;
            const int s = (i + 2) % 3;
            stage2(y, p, volBase + (long long)dd * planeStride,
                   &smem[s][0][0], &smem[s][1][0], wave, lane);
        }

        if (comp) {
            const float* curY = &smem[i % 3][0][0];
            const float* curP = &smem[i % 3][1][0];
            const float4 c0y = *(const float4*)(curY + sf);
            const float4 c0p = *(const float4*)(curP + sf);

            if (i >= 1) {
                // deferred D gradient for depth q = v-1: (c(q+1)-c(q-1))*sd
                const int q = d0 + i - 1;
                const float sd = (q == 0 || q == DDIM - 1) ? 1.f : 0.5f;
                float t0;
                t0 = fabsf((c0y.x - cm2y.x) * sd) - fabsf((c0p.x - cm2p.x) * sd); gd += t0 * t0;
                t0 = fabsf((c0y.y - cm2y.y) * sd) - fabsf((c0p.y - cm2p.y) * sd); gd += t0 * t0;
                t0 = fabsf((c0y.z - cm2y.z) * sd) - fabsf((c0p.z - cm2p.z) * sd); gd += t0 * t0;
                t0 = fabsf((c0y.w - cm2y.w) * sd) - fabsf((c0p.w - cm2p.w) * sd); gd += t0 * t0;
            }

            if (i < DC) {   // depth v belongs to this block: L1 + W + H now
                l1 += fabsf(c0y.x - c0p.x) + fabsf(c0y.y - c0p.y)
                    + fabsf(c0y.z - c0p.z) + fabsf(c0y.w - c0p.w);

                // W neighbors: shuffle + wave-boundary LDS patch + edge clamp
                float Ly = __shfl_up(c0y.w, 1, 64);
                float Lp = __shfl_up(c0p.w, 1, 64);
                float Ry = __shfl_down(c0y.x, 1, 64);
                float Rp = __shfl_down(c0p.x, 1, 64);
                if (needL) { Ly = curY[sf - 1]; Lp = curP[sf - 1]; }
                if (needR) { Ry = curY[sf + 4]; Rp = curP[sf + 4]; }
                Ly = gw ? Ly : c0y.x;             Lp = gw ? Lp : c0p.x;
                Ry = (gw == GW - 1) ? c0y.w : Ry; Rp = (gw == GW - 1) ? c0p.w : Rp;

                float t0, gy, gp;
                gy = (c0y.y - Ly) * swx;    gp = (c0p.y - Lp) * swx;
                t0 = fabsf(gy) - fabsf(gp); gd += t0 * t0;
                gy = (c0y.z - c0y.x) * 0.5f; gp = (c0p.z - c0p.x) * 0.5f;
                t0 = fabsf(gy) - fabsf(gp); gd += t0 * t0;
                gy = (c0y.w - c0y.y) * 0.5f; gp = (c0p.w - c0p.y) * 0.5f;
                t0 = fabsf(gy) - fabsf(gp); gd += t0 * t0;
                gy = (Ry - c0y.z) * sww;    gp = (Rp - c0p.z) * sww;
                t0 = fabsf(gy) - fabsf(gp); gd += t0 * t0;

                // H axis from LDS
                const float4 yhm = *(const float4*)(curY + sf + hmF);
                const float4 yhp = *(const float4*)(curY + sf + hpF);
                const float4 phm = *(const float4*)(curP + sf + hmF);
                const float4 php = *(const float4*)(curP + sf + hpF);
                t0 = fabsf((yhp.x - yhm.x) * sh) - fabsf((php.x - phm.x) * sh); gd += t0 * t0;
                t0 = fabsf((yhp.y - yhm.y) * sh) - fabsf((php.y - phm.y) * sh); gd += t0 * t0;
                t0 = fabsf((yhp.z - yhm.z) * sh) - fabsf((php.z - phm.z) * sh); gd += t0 * t0;
                t0 = fabsf((yhp.w - yhm.w) * sh) - fabsf((php.w - phm.w) * sh); gd += t0 * t0;
            }

            // rotate register D-pipeline
            cm2y = cm1y; cm1y = c0y;
            cm2p = cm1p; cm1p = c0p;
        }
    }

    // ---- block reduction (8 waves; idle waves contribute 0) ----
    __shared__ float red1[NWAVE], red2[NWAVE];
    #pragma unroll
    for (int off = 32; off > 0; off >>= 1) {
        l1 += __shfl_down(l1, off, 64);
        gd += __shfl_down(gd, off, 64);
    }
    if (lane == 0) { red1[wave] = l1; red2[wave] = gd; }
    __syncthreads();
    if (tid == 0) {
        float s1 = 0.f, s2 = 0.f;
        #pragma unroll
        for (int w = 0; w < NWAVE; ++w) { s1 += red1[w]; s2 += red2[w]; }
        part[2 * blockIdx.x]     = s1;
        part[2 * blockIdx.x + 1] = s2;
    }
}

// Reduce per-block partials + BCE over the small discriminator tensor.
__global__ __launch_bounds__(256) void finalize_kernel(const float* __restrict__ dsc,
                                                       const float* __restrict__ part,
                                                       float* __restrict__ out) {
    float l1 = 0.f, gd = 0.f, s = 0.f;
    for (int i = threadIdx.x; i < GRID; i += 256) {
        l1 += part[2 * i];
        gd += part[2 * i + 1];
    }
    for (int i = threadIdx.x; i < NDSC; i += 256) {
        const float x = dsc[i];
        // target is zeros: max(x,0) - x*0 + log1p(exp(-|x|))
        s += fmaxf(x, 0.f) + log1pf(expf(-fabsf(x)));
    }
    __shared__ float a[4], c[4], e[4];
    #pragma unroll
    for (int off = 32; off > 0; off >>= 1) {
        l1 += __shfl_down(l1, off, 64);
        gd += __shfl_down(gd, off, 64);
        s  += __shfl_down(s,  off, 64);
    }
    if ((threadIdx.x & 63) == 0) {
        const int w = threadIdx.x >> 6;
        a[w] = l1; c[w] = gd; e[w] = s;
    }
    __syncthreads();
    if (threadIdx.x == 0) {
        const float bce = (e[0] + e[1] + e[2] + e[3]) / (float)NDSC;
        const float l1m = (a[0] + a[1] + a[2] + a[3]) / (float)NTOT;
        const float gdm = (c[0] + c[1] + c[2] + c[3]) / (float)NTOT;
        out[0] = bce + 100.f * (l1m + gdm);
    }
}

extern "C" void kernel_launch(void* const* d_in, const int* in_sizes, int n_in,
                              void* d_out, int out_size, void* d_ws, size_t ws_size,
                              hipStream_t stream) {
    const float* dsc_fake = (const float*)d_in[0];
    const float* predicts = (const float*)d_in[1];
    const float* y_data   = (const float*)d_in[2];
    // d_in[3] (zeros) unused: target==0 makes the -x*target term vanish.
    float* part = (float*)d_ws;   // GRID*2 floats, fully overwritten each call
    float* out  = (float*)d_out;

    vol_kernel<<<GRID, BLOCK, 0, stream>>>(predicts, y_data, part);
    finalize_kernel<<<1, 256, 0, stream>>>(dsc_fake, part, out);
}

// Round 7
// 193.240 us; speedup vs baseline: 1.0198x; 1.0048x over previous
//
#include <hip/hip_runtime.h>
#include <math.h>

namespace {
constexpr int BATCH = 4;
constexpr int DDIM  = 128;
constexpr int HDIM  = 192;
constexpr int WDIM  = 192;
constexpr long long NTOT = (long long)BATCH * DDIM * HDIM * WDIM; // 18,874,368
constexpr int GW    = WDIM / 4;            // 48 float4 groups per W-row
constexpr int NDSC  = 4 * 1 * 8 * 12 * 12; // 4608
constexpr int TH    = 16;                  // computed rows per block
constexpr int SROWS = TH + 2;              // staged rows (H halo) = 18
constexpr int SGRP  = SROWS * GW;          // 864 float4 groups / slab
constexpr int SFL   = SGRP * 4;            // 3456 floats / slab (13,824 B)
constexpr int BLOCK = TH * GW;             // 768 threads = 12 waves, ALL compute
constexpr int NWAVE = BLOCK / 64;          // 12
constexpr int NCHUNK = (SGRP + 63) / 64;   // 14 (last chunk overlap-aligned back)
constexpr int DC    = 32;                  // depth steps per block
constexpr int GRID  = BATCH * (HDIM / TH) * (DDIM / DC); // 4*12*4 = 192
constexpr int DSCPB = NDSC / GRID;         // 24 dsc elements per block
}

__device__ __forceinline__ float4 ld4(const float* __restrict__ p, long long g) {
    return *(const float4*)(p + 4LL * g);
}

// DMA one contiguous slab (SROWS full-W rows at one depth) into LDS for both
// volumes. LDS dest = wave-uniform base + lane*16 (HW constraint), matching
// the slab's contiguous layout. Last chunk overlap-aligns backward (benign
// double-write of identical data).
__device__ __forceinline__ void stage2(const float* __restrict__ y,
                                       const float* __restrict__ p,
                                       long long fbase,
                                       float* ldsY, float* ldsP,
                                       int wave, int lane) {
    for (int c = wave; c < NCHUNK; c += NWAVE) {
        const int gbase = (c == NCHUNK - 1) ? (SGRP - 64) : (c * 64);
        __builtin_amdgcn_global_load_lds(
            (const __attribute__((address_space(1))) void*)(y + fbase + 4LL * (gbase + lane)),
            (__attribute__((address_space(3))) void*)(ldsY + 4 * gbase), 16, 0, 0);
        __builtin_amdgcn_global_load_lds(
            (const __attribute__((address_space(1))) void*)(p + fbase + 4LL * (gbase + lane)),
            (__attribute__((address_space(3))) void*)(ldsP + 4 * gbase), 16, 0, 0);
    }
}

// Demand-minimized plane-streaming stencil (the ~3.3 TB/s fabric wall is the
// limiter, so halo bytes are the only lever):
//   tile = 16 rows x full W x 32 depths -> halo factor (18/16)*(33/32) = 1.16.
//   2-slab LDS ring, one plane staged ahead, __syncthreads per plane.
//   D-gradient deferred one step via a register pipeline; W via shuffles;
//   H from LDS. np.gradient edges branchless (clamp + scale 1 / 0.5).
// Epilogue fused: per-block partials + a 24-element BCE slice are atomically
// accumulated; the last block (device-scope ticket) writes the final scalar.
__global__ __launch_bounds__(BLOCK) void vol_kernel(const float* __restrict__ p,
                                                    const float* __restrict__ y,
                                                    const float* __restrict__ dsc,
                                                    float* __restrict__ acc,
                                                    int* __restrict__ ticket,
                                                    float* __restrict__ out) {
    __shared__ __align__(16) float smem[2][2][SFL];   // 55,296 B

    int bid = blockIdx.x;
    const int dIdx = bid % (DDIM / DC); bid /= (DDIM / DC);
    const int hIdx = bid % (HDIM / TH); bid /= (HDIM / TH);
    const int b    = bid;
    const int d0   = dIdx * DC;
    const int h0   = hIdx * TH;

    const int tid  = threadIdx.x;
    const int lane = tid & 63;
    const int wave = tid >> 6;

    const int g0 = (h0 == 0) ? 0 : ((h0 == HDIM - TH) ? (HDIM - SROWS) : (h0 - 1));
    const long long planeStride = (long long)HDIM * WDIM;
    const long long volBase = (long long)b * DDIM * planeStride + (long long)g0 * WDIM;

    // prologue: DMA plane d0 into slab 0
    stage2(y, p, volBase + (long long)d0 * planeStride,
           &smem[0][0][0], &smem[0][1][0], wave, lane);

    // per-thread constants
    const int r  = tid / GW;           // 0..15
    const int gw = tid % GW;
    const int h  = h0 + r;
    const int rowOff = h0 - g0;                      // 0 / 1 / 2
    const int sf  = ((r + rowOff) * GW + gw) * 4;    // own float offset in slab
    const int hmF = ((h == 0)        ? 0 : -GW) * 4;
    const int hpF = ((h == HDIM - 1) ? 0 :  GW) * 4;
    const float sh  = (h == 0 || h == HDIM - 1) ? 1.f : 0.5f;
    const float swx = (gw == 0)      ? 1.f : 0.5f;
    const float sww = (gw == GW - 1) ? 1.f : 0.5f;
    const bool needL = (lane == 0)  && (gw > 0);
    const bool needR = (lane == 63) && (gw < GW - 1);

    // register D-pipeline seed: plane d0-1 (clamped), own column
    const int dm = (d0 > 0) ? (d0 - 1) : 0;
    const long long gown = (((long long)b * DDIM + dm) * HDIM + h) * GW + gw;
    float4 cm1y = ld4(y, gown), cm1p = ld4(p, gown);
    float4 cm2y, cm2p;

    // BCE slice for this block (loads overlap the prologue DMA)
    float bc = 0.f;
    if (tid < DSCPB) {
        const float x = dsc[blockIdx.x * DSCPB + tid];
        bc = fmaxf(x, 0.f) + log1pf(expf(-fabsf(x)));
    }

    float l1 = 0.f, gd = 0.f;

    for (int i = 0; i <= DC; ++i) {
        __syncthreads();   // drains DMA for plane v (slab i&1); frees slab (i+1)&1

        if (i < DC) {      // stage plane v+1 into the other slab (clamped at top)
            int dd = d0 + i + 1; if (dd > DDIM - 1) dd = DDIM - 1;
            const int s = (i + 1) & 1;
            stage2(y, p, volBase + (long long)dd * planeStride,
                   &smem[s][0][0], &smem[s][1][0], wave, lane);
        }

        const float* curY = &smem[i & 1][0][0];
        const float* curP = &smem[i & 1][1][0];
        const float4 c0y = *(const float4*)(curY + sf);
        const float4 c0p = *(const float4*)(curP + sf);

        if (i >= 1) {
            // deferred D gradient for depth q = v-1: (c(q+1)-c(q-1))*sd
            const int q = d0 + i - 1;
            const float sd = (q == 0 || q == DDIM - 1) ? 1.f : 0.5f;
            float t0;
            t0 = fabsf((c0y.x - cm2y.x) * sd) - fabsf((c0p.x - cm2p.x) * sd); gd += t0 * t0;
            t0 = fabsf((c0y.y - cm2y.y) * sd) - fabsf((c0p.y - cm2p.y) * sd); gd += t0 * t0;
            t0 = fabsf((c0y.z - cm2y.z) * sd) - fabsf((c0p.z - cm2p.z) * sd); gd += t0 * t0;
            t0 = fabsf((c0y.w - cm2y.w) * sd) - fabsf((c0p.w - cm2p.w) * sd); gd += t0 * t0;
        }

        if (i < DC) {   // depth v: L1 + W + H now
            l1 += fabsf(c0y.x - c0p.x) + fabsf(c0y.y - c0p.y)
                + fabsf(c0y.z - c0p.z) + fabsf(c0y.w - c0p.w);

            // W neighbors: shuffle + wave-boundary LDS patch + edge clamp
            float Ly = __shfl_up(c0y.w, 1, 64);
            float Lp = __shfl_up(c0p.w, 1, 64);
            float Ry = __shfl_down(c0y.x, 1, 64);
            float Rp = __shfl_down(c0p.x, 1, 64);
            if (needL) { Ly = curY[sf - 1]; Lp = curP[sf - 1]; }
            if (needR) { Ry = curY[sf + 4]; Rp = curP[sf + 4]; }
            Ly = gw ? Ly : c0y.x;             Lp = gw ? Lp : c0p.x;
            Ry = (gw == GW - 1) ? c0y.w : Ry; Rp = (gw == GW - 1) ? c0p.w : Rp;

            float t0, gy, gp;
            gy = (c0y.y - Ly) * swx;     gp = (c0p.y - Lp) * swx;
            t0 = fabsf(gy) - fabsf(gp);  gd += t0 * t0;
            gy = (c0y.z - c0y.x) * 0.5f; gp = (c0p.z - c0p.x) * 0.5f;
            t0 = fabsf(gy) - fabsf(gp);  gd += t0 * t0;
            gy = (c0y.w - c0y.y) * 0.5f; gp = (c0p.w - c0p.y) * 0.5f;
            t0 = fabsf(gy) - fabsf(gp);  gd += t0 * t0;
            gy = (Ry - c0y.z) * sww;     gp = (Rp - c0p.z) * sww;
            t0 = fabsf(gy) - fabsf(gp);  gd += t0 * t0;

            // H axis from LDS
            const float4 yhm = *(const float4*)(curY + sf + hmF);
            const float4 yhp = *(const float4*)(curY + sf + hpF);
            const float4 phm = *(const float4*)(curP + sf + hmF);
            const float4 php = *(const float4*)(curP + sf + hpF);
            t0 = fabsf((yhp.x - yhm.x) * sh) - fabsf((php.x - phm.x) * sh); gd += t0 * t0;
            t0 = fabsf((yhp.y - yhm.y) * sh) - fabsf((php.y - phm.y) * sh); gd += t0 * t0;
            t0 = fabsf((yhp.z - yhm.z) * sh) - fabsf((php.z - phm.z) * sh); gd += t0 * t0;
            t0 = fabsf((yhp.w - yhm.w) * sh) - fabsf((php.w - phm.w) * sh); gd += t0 * t0;
        }

        // rotate register D-pipeline
        cm2y = cm1y; cm1y = c0y;
        cm2p = cm1p; cm1p = c0p;
    }

    // ---- block reduction (12 waves) + device-scope accumulate + ticket ----
    __shared__ float r1[NWAVE], r2[NWAVE], r3[NWAVE];
    #pragma unroll
    for (int off = 32; off > 0; off >>= 1) {
        l1 += __shfl_down(l1, off, 64);
        gd += __shfl_down(gd, off, 64);
        bc += __shfl_down(bc, off, 64);
    }
    if (lane == 0) { r1[wave] = l1; r2[wave] = gd; r3[wave] = bc; }
    __syncthreads();
    if (tid == 0) {
        float s1 = 0.f, s2 = 0.f, s3 = 0.f;
        #pragma unroll
        for (int w = 0; w < NWAVE; ++w) { s1 += r1[w]; s2 += r2[w]; s3 += r3[w]; }
        atomicAdd(&acc[0], s1);
        atomicAdd(&acc[1], s2);
        atomicAdd(&acc[2], s3);
        __threadfence();
        const int t = atomicAdd(ticket, 1);
        if (t == GRID - 1) {   // last block: all adds are visible; finalize
            const float L = atomicAdd(&acc[0], 0.f);   // coherent device-scope reads
            const float G = atomicAdd(&acc[1], 0.f);
            const float B = atomicAdd(&acc[2], 0.f);
            out[0] = B / (float)NDSC + 100.f * ((L + G) / (float)NTOT);
        }
    }
}

extern "C" void kernel_launch(void* const* d_in, const int* in_sizes, int n_in,
                              void* d_out, int out_size, void* d_ws, size_t ws_size,
                              hipStream_t stream) {
    const float* dsc_fake = (const float*)d_in[0];
    const float* predicts = (const float*)d_in[1];
    const float* y_data   = (const float*)d_in[2];
    // d_in[3] (zeros) unused: target==0 makes the -x*target term vanish.
    float* acc    = (float*)d_ws;          // acc[0]=l1, acc[1]=gd, acc[2]=bce
    int*   ticket = (int*)((char*)d_ws + 3 * sizeof(float));
    float* out    = (float*)d_out;

    hipMemsetAsync(d_ws, 0, 4 * sizeof(float), stream);  // zero acc + ticket
    vol_kernel<<<GRID, BLOCK, 0, stream>>>(predicts, y_data, dsc_fake, acc, ticket, out);
}